// Round 3
// baseline (1383.899 us; speedup 1.0000x reference)
//
#include <hip/hip_runtime.h>
#include <cmath>

// MZILinear: out = x @ W^T, W = diag(dU)*Ru*diag(sigma*dV)*Rv,
// Ru/Rv = product of 130816 Givens rotations (Reck order) applied to I.
//
// Pipeline:
//  1) trig_kernel  : (c,s) pairs for both phi arrays
//  2) group_kernel : split rotation sequence into G contiguous blocks, build
//                    each block product from identity. v2: flat batched stream,
//                    double-buffered register prefetch of the LDS column state
//                    (breaks the 120-cyc ds_read latency serialization).
//  3) combine_kernel (log2 G rounds): tree-multiply block products
//  4) wasm_kernel  : W = diag(dU) * Ru * diag(sigma*dV) * Rv
//  5) gemm_kernel  : out[32768,512] = x * W^T (fp32 VALU, 128x64 tile)

#define NDIM 512
#define NPAIR 130816            // 512*511/2
#define MAT (NDIM * NDIM)       // 262144 floats per matrix slot

// T(i) = number of rotations before pivot i starts = i*(1023-i)/2
__device__ __forceinline__ int T_of(int i) { return (i * (1023 - i)) >> 1; }

// largest i with T(i) <= k
__device__ __forceinline__ int pivot_of(int k) {
    int lo = 0, hi = 511;
    while (lo < hi) {
        int mid = (lo + hi + 1) >> 1;
        if (T_of(mid) <= k) lo = mid; else hi = mid - 1;
    }
    return lo;
}

// ---------------------------------------------------------------- trig
__global__ __launch_bounds__(256) void trig_kernel(const float* __restrict__ pU,
                                                   const float* __restrict__ pV,
                                                   float2* __restrict__ csU,
                                                   float2* __restrict__ csV) {
    int idx = blockIdx.x * 256 + threadIdx.x;
    if (idx < NPAIR) {
        float s, c;
        sincosf(pU[idx], &s, &c);
        csU[idx] = make_float2(c, s);
    } else if (idx < 2 * NPAIR) {
        int m = idx - NPAIR;
        float s, c;
        sincosf(pV[m], &s, &c);
        csV[m] = make_float2(c, s);
    }
}

// ---------------------------------------------------------------- group products
// One wave per block, 32 active lanes = 32 columns; state v[row][lane] in LDS.
// Rotation k of pivot p at row q: vj=state[q]; vjn=s*vi+c*vj; vin=c*vi-s*vj;
// normal: state[q]=vjn, vi=vin.  boundary (q==p+1): state[p]=vin, vi=vjn
// (the new pivot's row value is carried in-register; its LDS copy is stale but
// never read until its own pivot closes).
//
// Batched pipeline: process 8 rotations per batch; prefetch the next batch's
// 8 row values + (c,s) while the current batch's 4-cyc FMA chain runs.
// Safety: a prefetched row must not be written between prefetch and use.
// Same-row reuse distance = pivot length (511-i); prefetch window is <16
// rotations, so the batched path is valid while pivot <= 495 (k < T(496)).
// The remaining <=120 rotations (last group only) use the scalar path.

#define GK_LOAD(R_, C_, S_, W_, B_)                                   \
    {                                                                 \
        _Pragma("unroll")                                             \
        for (int u = 0; u < 8; ++u) {                                 \
            int bnd = (pj == pi + 1);                                 \
            R_[u] = v[pj * 32 + lane];                                \
            float2 cs2 = csp[kp + u];                                 \
            C_[u] = cs2.x; S_[u] = cs2.y;                             \
            W_[u] = bnd ? pi : pj;                                    \
            B_[u] = bnd;                                              \
            pi += bnd;                                                \
            pj = bnd ? 511 : (pj - 1);                                \
        }                                                             \
        kp += 8;                                                      \
    }

#define GK_COMP(R_, C_, S_, W_, B_)                                   \
    {                                                                 \
        _Pragma("unroll")                                             \
        for (int u = 0; u < 8; ++u) {                                 \
            float vj  = R_[u];                                        \
            float vjn = fmaf(S_[u], vi, C_[u] * vj);                  \
            float vin = fmaf(C_[u], vi, -(S_[u] * vj));               \
            v[W_[u] * 32 + lane] = B_[u] ? vin : vjn;                 \
            vi = B_[u] ? vjn : vin;                                   \
        }                                                             \
    }

__global__ __launch_bounds__(64) void group_kernel(const float2* __restrict__ csU,
                                                   const float2* __restrict__ csV,
                                                   float* __restrict__ bufA,
                                                   int R, int capA) {
    __shared__ float v[NDIM * 32];
    const int lane = threadIdx.x;
    if (lane >= 32) return;                    // half-wave active; no barriers used
    const int col0 = blockIdx.x * 32;
    const int col  = col0 + lane;
    const int g    = blockIdx.y;
    const int side = blockIdx.z;               // 0 = U, 1 = V
    const int k0 = g * R, k1 = k0 + R;
    const int i0 = pivot_of(k0);
    float* out = bufA + ((size_t)(side * capA + g)) * MAT;

    if (col0 + 32 <= i0) {                     // columns < first pivot: identity
        for (int r = 0; r < NDIM; ++r)
            out[(size_t)r * NDIM + col] = (r == col) ? 1.f : 0.f;
        return;
    }
    const float2* __restrict__ csp = side ? csV : csU;

    for (int r = 0; r < NDIM; ++r)             // column state = e_col
        v[r * 32 + lane] = (r == col) ? 1.f : 0.f;

    int i = i0;
    int j = 511 - (k0 - T_of(i0));
    int k = k0;

    // ---- batched pipelined main (pivots <= 495) ----
    const int kSafe = T_of(496);
    const int kEnd = (k1 < kSafe) ? k1 : kSafe;
    const int nb = (kEnd > k) ? (kEnd - k) / 8 : 0;
    if (nb > 0) {
        float vi = v[i * 32 + lane];
        int pi = i, pj = j, kp = k;
        float rA[8], rB[8], cA[8], sA[8], cB[8], sB[8];
        int wA[8], wB[8], bA[8], bB[8];
        GK_LOAD(rA, cA, sA, wA, bA);
        for (int b = 1; b < nb; ++b) {
            if (b & 1) { GK_LOAD(rB, cB, sB, wB, bB); GK_COMP(rA, cA, sA, wA, bA); }
            else       { GK_LOAD(rA, cA, sA, wA, bA); GK_COMP(rB, cB, sB, wB, bB); }
        }
        if (nb & 1) { GK_COMP(rA, cA, sA, wA, bA); }
        else        { GK_COMP(rB, cB, sB, wB, bB); }
        k = kp; i = pi; j = pj;
        v[i * 32 + lane] = vi;                 // materialize current pivot row
    }

    // ---- scalar tail (unsafe zone + <8 leftovers) ----
    while (k < k1 && i < 511) {
        float vi = v[i * 32 + lane];
        int cnt = min(k1 - k, j - i);
        for (int t = 0; t < cnt; ++t) {
            float2 cs = csp[k + t];
            float vj  = v[(j - t) * 32 + lane];
            float vjn = fmaf(cs.y, vi, cs.x * vj);
            vi        = fmaf(cs.x, vi, -(cs.y * vj));
            v[(j - t) * 32 + lane] = vjn;
        }
        k += cnt; j -= cnt;
        v[i * 32 + lane] = vi;
        if (j == i) { ++i; j = 511; }
    }

    for (int r = 0; r < NDIM; ++r)
        out[(size_t)r * NDIM + col] = v[r * 32 + lane];
}

// ---------------------------------------------------------------- combine rounds
// C[m] = src[2m+1] * src[2m]  (X = later rotation block = left operand).
// X is identity on rows < ax; Y is identity on cols < ay.
__global__ __launch_bounds__(256) void combine_kernel(const float* __restrict__ src,
                                                      float* __restrict__ dst,
                                                      int srcCap, int dstCap,
                                                      int half, int R, int P) {
    const int side = blockIdx.z / P, m = blockIdx.z % P;
    const int bx = blockIdx.x & 7, by = blockIdx.x >> 3;
    const int row0 = by * 64, col0 = bx * 64;
    const float* __restrict__ X = src + ((size_t)(side * srcCap + 2 * m + 1)) * MAT;
    const float* __restrict__ Y = src + ((size_t)(side * srcCap + 2 * m)) * MAT;
    float* __restrict__ C = dst + ((size_t)(side * dstCap + m)) * MAT;
    const int ax = pivot_of((2 * m * half + half) * R);
    const int ay = pivot_of((2 * m * half) * R);
    const int tid = threadIdx.x;

    if (row0 + 64 <= ax) {                     // X rows identity -> C tile = Y tile
        for (int t = tid; t < 64 * 16; t += 256) {
            int r = t >> 4, q = (t & 15) * 4;
            size_t off = (size_t)(row0 + r) * NDIM + col0 + q;
            *(float4*)&C[off] = *(const float4*)&Y[off];
        }
        return;
    }
    if (col0 + 64 <= ay) {                     // Y cols identity -> C tile = X tile
        for (int t = tid; t < 64 * 16; t += 256) {
            int r = t >> 4, q = (t & 15) * 4;
            size_t off = (size_t)(row0 + r) * NDIM + col0 + q;
            *(float4*)&C[off] = *(const float4*)&X[off];
        }
        return;
    }

    __shared__ float Xs[64][36];
    __shared__ float Ys[32][68];
    const int tx = tid & 15, ty = tid >> 4;
    float acc[4][4] = {};
    // rows >= ax have X[r,k<ax] == 0 -> start K loop at ax (rounded down to 32)
    const int kt0 = (row0 >= ax) ? (ax >> 5) : 0;
    for (int kt = kt0; kt < 16; ++kt) {
        {
            int r = tid >> 2, q = (tid & 3) * 4;
            const float* xr = X + (size_t)(row0 + r) * NDIM + kt * 32;
            *(float4*)&Xs[r][q]      = *(const float4*)(xr + q);
            *(float4*)&Xs[r][q + 16] = *(const float4*)(xr + q + 16);
        }
        {
            int kk = tid >> 4, cq = (tid & 15) * 4;
            *(float4*)&Ys[kk][cq]      = *(const float4*)(Y + (size_t)(kt * 32 + kk) * NDIM + col0 + cq);
            *(float4*)&Ys[kk + 16][cq] = *(const float4*)(Y + (size_t)(kt * 32 + kk + 16) * NDIM + col0 + cq);
        }
        __syncthreads();
        #pragma unroll
        for (int kk = 0; kk < 32; ++kk) {
            float av[4] = {Xs[ty * 4 + 0][kk], Xs[ty * 4 + 1][kk],
                           Xs[ty * 4 + 2][kk], Xs[ty * 4 + 3][kk]};
            float4 B = *(const float4*)&Ys[kk][tx * 4];
            float bv[4] = {B.x, B.y, B.z, B.w};
            #pragma unroll
            for (int mm = 0; mm < 4; ++mm)
                #pragma unroll
                for (int nn = 0; nn < 4; ++nn)
                    acc[mm][nn] = fmaf(av[mm], bv[nn], acc[mm][nn]);
        }
        __syncthreads();
    }
    #pragma unroll
    for (int mm = 0; mm < 4; ++mm) {
        float4 st = make_float4(acc[mm][0], acc[mm][1], acc[mm][2], acc[mm][3]);
        *(float4*)&C[(size_t)(row0 + ty * 4 + mm) * NDIM + col0 + tx * 4] = st;
    }
}

// ---------------------------------------------------------------- W assembly
// W = diag(dU) * Ru * diag(sigma*dV) * Rv
__global__ __launch_bounds__(256) void wasm_kernel(const float* __restrict__ Ru,
                                                   const float* __restrict__ Rv,
                                                   const float* __restrict__ dU,
                                                   const float* __restrict__ dV,
                                                   const float* __restrict__ sg,
                                                   float* __restrict__ W) {
    const int bx = blockIdx.x & 7, by = blockIdx.x >> 3;
    const int row0 = by * 64, col0 = bx * 64;
    __shared__ float Xs[64][36];
    __shared__ float Ys[32][68];
    const int tid = threadIdx.x;
    const int tx = tid & 15, ty = tid >> 4;
    float acc[4][4] = {};
    for (int kt = 0; kt < 16; ++kt) {
        {
            int r = tid >> 2, q = (tid & 3) * 4;
            const float* xr = Ru + (size_t)(row0 + r) * NDIM + kt * 32;
            *(float4*)&Xs[r][q]      = *(const float4*)(xr + q);
            *(float4*)&Xs[r][q + 16] = *(const float4*)(xr + q + 16);
        }
        {
            int kk = tid >> 4, cq = (tid & 15) * 4;
            int kg = kt * 32 + kk;
            float sd = sg[kg] * dV[kg];
            float4 b = *(const float4*)(Rv + (size_t)kg * NDIM + col0 + cq);
            b.x *= sd; b.y *= sd; b.z *= sd; b.w *= sd;
            *(float4*)&Ys[kk][cq] = b;
            int kg2 = kg + 16;
            float sd2 = sg[kg2] * dV[kg2];
            float4 b2 = *(const float4*)(Rv + (size_t)kg2 * NDIM + col0 + cq);
            b2.x *= sd2; b2.y *= sd2; b2.z *= sd2; b2.w *= sd2;
            *(float4*)&Ys[kk + 16][cq] = b2;
        }
        __syncthreads();
        #pragma unroll
        for (int kk = 0; kk < 32; ++kk) {
            float av[4] = {Xs[ty * 4 + 0][kk], Xs[ty * 4 + 1][kk],
                           Xs[ty * 4 + 2][kk], Xs[ty * 4 + 3][kk]};
            float4 B = *(const float4*)&Ys[kk][tx * 4];
            float bv[4] = {B.x, B.y, B.z, B.w};
            #pragma unroll
            for (int mm = 0; mm < 4; ++mm)
                #pragma unroll
                for (int nn = 0; nn < 4; ++nn)
                    acc[mm][nn] = fmaf(av[mm], bv[nn], acc[mm][nn]);
        }
        __syncthreads();
    }
    #pragma unroll
    for (int mm = 0; mm < 4; ++mm) {
        float du = dU[row0 + ty * 4 + mm];
        float4 st = make_float4(acc[mm][0] * du, acc[mm][1] * du,
                                acc[mm][2] * du, acc[mm][3] * du);
        *(float4*)&W[(size_t)(row0 + ty * 4 + mm) * NDIM + col0 + tx * 4] = st;
    }
}

// ---------------------------------------------------------------- final GEMM
// out[t,o] = sum_i x[t,i] * W[o,i].  128x64 tile, BK=32, 8x4 micro-tile.
__global__ __launch_bounds__(256) void gemm_kernel(const float* __restrict__ x,
                                                   const float* __restrict__ W,
                                                   float* __restrict__ out) {
    const int col0 = blockIdx.x * 64;
    const int row0 = blockIdx.y * 128;
    __shared__ float Xs[32][132];   // [k][token]
    __shared__ float Ys[32][68];    // [k][outcol]
    const int tid = threadIdx.x;
    const int tx = tid & 15, ty = tid >> 4;
    float acc[8][4] = {};
    for (int kt = 0; kt < 16; ++kt) {
        {
            int r = tid & 127;
            int ks = (tid >> 7) * 16;
            const float* xr = x + (size_t)(row0 + r) * NDIM + kt * 32 + ks;
            #pragma unroll
            for (int u = 0; u < 4; ++u) {
                float4 vv = *(const float4*)(xr + u * 4);
                Xs[ks + u * 4 + 0][r] = vv.x;
                Xs[ks + u * 4 + 1][r] = vv.y;
                Xs[ks + u * 4 + 2][r] = vv.z;
                Xs[ks + u * 4 + 3][r] = vv.w;
            }
        }
        {
            int o = tid & 63;
            int ks = (tid >> 6) * 4;
            const float* wr = W + (size_t)(col0 + o) * NDIM + kt * 32;
            float4 w0 = *(const float4*)(wr + ks);
            float4 w1 = *(const float4*)(wr + ks + 16);
            Ys[ks + 0][o] = w0.x; Ys[ks + 1][o] = w0.y;
            Ys[ks + 2][o] = w0.z; Ys[ks + 3][o] = w0.w;
            Ys[ks + 16][o] = w1.x; Ys[ks + 17][o] = w1.y;
            Ys[ks + 18][o] = w1.z; Ys[ks + 19][o] = w1.w;
        }
        __syncthreads();
        #pragma unroll
        for (int kk = 0; kk < 32; ++kk) {
            float4 A0 = *(const float4*)&Xs[kk][ty * 8];
            float4 A1 = *(const float4*)&Xs[kk][ty * 8 + 4];
            float4 B  = *(const float4*)&Ys[kk][tx * 4];
            float av[8] = {A0.x, A0.y, A0.z, A0.w, A1.x, A1.y, A1.z, A1.w};
            float bv[4] = {B.x, B.y, B.z, B.w};
            #pragma unroll
            for (int mm = 0; mm < 8; ++mm)
                #pragma unroll
                for (int nn = 0; nn < 4; ++nn)
                    acc[mm][nn] = fmaf(av[mm], bv[nn], acc[mm][nn]);
        }
        __syncthreads();
    }
    #pragma unroll
    for (int mm = 0; mm < 8; ++mm) {
        float4 st = make_float4(acc[mm][0], acc[mm][1], acc[mm][2], acc[mm][3]);
        *(float4*)&out[(size_t)(row0 + ty * 8 + mm) * NDIM + col0 + tx * 4] = st;
    }
}

// ---------------------------------------------------------------- host
extern "C" void kernel_launch(void* const* d_in, const int* in_sizes, int n_in,
                              void* d_out, int out_size, void* d_ws, size_t ws_size,
                              hipStream_t stream) {
    (void)in_sizes; (void)n_in; (void)out_size;
    const float* xp   = (const float*)d_in[0];
    const float* phiU = (const float*)d_in[1];
    const float* dUp  = (const float*)d_in[2];
    const float* phiV = (const float*)d_in[3];
    const float* dVp  = (const float*)d_in[4];
    const float* sgp  = (const float*)d_in[5];
    float* out = (float*)d_out;
    float* wsf = (float*)d_ws;

    // Pick largest G (rotation blocks per matrix) that fits the workspace.
    int G = 16;
    while (G > 1) {
        size_t needFloats = (size_t)4 * NPAIR + (size_t)2 * G * MAT
                          + (size_t)G * MAT + MAT;
        if (needFloats * 4 <= ws_size) break;
        G >>= 1;
    }
    const int R = NPAIR / G;   // exact for G in {1,2,4,8,16}

    float2* csU = (float2*)wsf;
    float2* csV = csU + NPAIR;
    float* bufA = wsf + (size_t)4 * NPAIR;
    float* bufB = bufA + (size_t)2 * G * MAT;
    const int capB = (G > 1) ? G / 2 : 1;
    float* Wbuf = (G > 1) ? (bufB + (size_t)2 * capB * MAT) : bufB;

    // 1) trig
    trig_kernel<<<dim3((2 * NPAIR + 255) / 256), 256, 0, stream>>>(phiU, phiV, csU, csV);

    // 2) block products (both sides in one launch)
    group_kernel<<<dim3(16, G, 2), 64, 0, stream>>>(csU, csV, bufA, R, G);

    // 3) tree combine: log2(G) rounds, ping-pong bufA <-> bufB
    const float* cur = bufA;
    float* oth = bufB;
    int curCap = G, othCap = capB;
    for (int P = G / 2, half = 1; P >= 1; P >>= 1, half <<= 1) {
        combine_kernel<<<dim3(64, 1, 2 * P), 256, 0, stream>>>(cur, oth, curCap, othCap, half, R, P);
        const float* t = cur; cur = oth; oth = (float*)t;
        int tc = curCap; curCap = othCap; othCap = tc;
    }
    const float* Ru = cur;
    const float* Rv = cur + (size_t)curCap * MAT;

    // 4) W assembly
    wasm_kernel<<<dim3(64), 256, 0, stream>>>(Ru, Rv, dUp, dVp, sgp, Wbuf);

    // 5) out = x * W^T
    gemm_kernel<<<dim3(8, 256), 256, 0, stream>>>(xp, Wbuf, out);
}

// Round 4
// 952.873 us; speedup vs baseline: 1.4523x; 1.4523x over previous
//
#include <hip/hip_runtime.h>
#include <cmath>

// MZILinear: out = x @ W^T, W = diag(dU)*Ru*diag(sigma*dV)*Rv,
// Ru/Rv = product of 130816 Givens rotations (Reck order) applied to I.
//
// Pipeline:
//  1) trig_kernel  : (c,s) pairs for both phi arrays
//  2) group_kernel : split rotation sequence into G contiguous blocks, build
//                    each block product from identity. v3: per-pivot inner fan
//                    software-pipelined with an 8-deep static-index prefetch
//                    ring (v2's array/macro version spilled to scratch and
//                    regressed 417->906us; this keeps ring state in registers).
//  3) combine_kernel (log2 G rounds): tree-multiply block products
//  4) wasm_kernel  : W = diag(dU) * Ru * diag(sigma*dV) * Rv
//  5) gemm_kernel  : out[32768,512] = x * W^T (fp32 VALU, 128x64 tile)

#define NDIM 512
#define NPAIR 130816            // 512*511/2
#define MAT (NDIM * NDIM)       // 262144 floats per matrix slot

// T(i) = number of rotations before pivot i starts = i*(1023-i)/2
__device__ __forceinline__ int T_of(int i) { return (i * (1023 - i)) >> 1; }

// largest i with T(i) <= k
__device__ __forceinline__ int pivot_of(int k) {
    int lo = 0, hi = 511;
    while (lo < hi) {
        int mid = (lo + hi + 1) >> 1;
        if (T_of(mid) <= k) lo = mid; else hi = mid - 1;
    }
    return lo;
}

// ---------------------------------------------------------------- trig
__global__ __launch_bounds__(256) void trig_kernel(const float* __restrict__ pU,
                                                   const float* __restrict__ pV,
                                                   float2* __restrict__ csU,
                                                   float2* __restrict__ csV) {
    int idx = blockIdx.x * 256 + threadIdx.x;
    if (idx < NPAIR) {
        float s, c;
        sincosf(pU[idx], &s, &c);
        csU[idx] = make_float2(c, s);
    } else if (idx < 2 * NPAIR) {
        int m = idx - NPAIR;
        float s, c;
        sincosf(pV[m], &s, &c);
        csV[m] = make_float2(c, s);
    }
}

// ---------------------------------------------------------------- group products
// One wave per block, 32 active lanes = 32 columns; state v[row][lane] in LDS.
// Per pivot i, rotations sweep rows j = hi..i+1.  Only the pivot-row value vi
// chains serially (2 dependent FMAs/rot); the vj reads are independent row
// addresses, so they are prefetched 8 deep.  Ring buffers are fixed-size and
// only ever indexed by compile-time constants (unrolled), so they live in
// registers.  Prefetch of row (j - t - 8) is safe: that row's own write is
// 8 iterations ahead, and nothing else writes it within the pivot.
__global__ __launch_bounds__(64) void group_kernel(const float2* __restrict__ csU,
                                                   const float2* __restrict__ csV,
                                                   float* __restrict__ bufA,
                                                   int R, int capA) {
    __shared__ float v[NDIM * 32];
    const int lane = threadIdx.x;
    if (lane >= 32) return;                    // half-wave active; no barriers used
    const int col0 = blockIdx.x * 32;
    const int col  = col0 + lane;
    const int g    = blockIdx.y;
    const int side = blockIdx.z;               // 0 = U, 1 = V
    const int k0 = g * R, k1 = k0 + R;
    const int i0 = pivot_of(k0);
    float* out = bufA + ((size_t)(side * capA + g)) * MAT;

    if (col0 + 32 <= i0) {                     // columns < first pivot: identity
        for (int r = 0; r < NDIM; ++r)
            out[(size_t)r * NDIM + col] = (r == col) ? 1.f : 0.f;
        return;
    }
    const float2* __restrict__ csp = side ? csV : csU;

    for (int r = 0; r < NDIM; ++r)             // column state = e_col
        v[r * 32 + lane] = (r == col) ? 1.f : 0.f;

    int i = i0;
    int j = 511 - (k0 - T_of(i0));
    int k = k0;
    while (k < k1 && i < 511) {
        float vi = v[i * 32 + lane];
        const int cnt = min(k1 - k, j - i);    // rotations in this pivot/group
        float2 csb[8], csc[8];
        float  vjb[8], vjc[8];

        // prologue: fill ring with t = 0..7
        #pragma unroll
        for (int u = 0; u < 8; ++u) {
            if (u < cnt) {
                csb[u] = csp[k + u];
                vjb[u] = v[(j - u) * 32 + lane];
            }
        }

        // main: t in [0, nf8), always 8-deep prefetch.  nf8 = multiple of 8.
        const int nf8 = (cnt > 8) ? ((cnt - 8) & ~7) : 0;
        for (int tb = 0; tb < nf8; tb += 8) {
            #pragma unroll
            for (int u = 0; u < 8; ++u) {
                const int t = tb + u;
                const float c = csb[u].x, s = csb[u].y, vj = vjb[u];
                csb[u] = csp[k + t + 8];                 // in-bounds: t+8 < cnt
                vjb[u] = v[(j - t - 8) * 32 + lane];     // row >= i+1
                const float vjn = fmaf(s, vi, c * vj);
                vi = fmaf(c, vi, -(s * vj));
                v[(j - t) * 32 + lane] = vjn;
            }
        }

        // epilogue A: consume buffered t = nf8+u, prefetch t+8 into second ring
        #pragma unroll
        for (int u = 0; u < 8; ++u) {
            const int t = nf8 + u;
            if (t < cnt) {
                const float c = csb[u].x, s = csb[u].y, vj = vjb[u];
                if (t + 8 < cnt) {
                    csc[u] = csp[k + t + 8];
                    vjc[u] = v[(j - t - 8) * 32 + lane];
                }
                const float vjn = fmaf(s, vi, c * vj);
                vi = fmaf(c, vi, -(s * vj));
                v[(j - t) * 32 + lane] = vjn;
            }
        }
        // epilogue B: consume second ring, t = nf8+8+u  (cnt - nf8 <= 15)
        #pragma unroll
        for (int u = 0; u < 8; ++u) {
            const int t = nf8 + 8 + u;
            if (t < cnt) {
                const float c = csc[u].x, s = csc[u].y, vj = vjc[u];
                const float vjn = fmaf(s, vi, c * vj);
                vi = fmaf(c, vi, -(s * vj));
                v[(j - t) * 32 + lane] = vjn;
            }
        }

        k += cnt; j -= cnt;
        v[i * 32 + lane] = vi;
        if (j == i) { ++i; j = 511; }
    }

    for (int r = 0; r < NDIM; ++r)
        out[(size_t)r * NDIM + col] = v[r * 32 + lane];
}

// ---------------------------------------------------------------- combine rounds
// C[m] = src[2m+1] * src[2m]  (X = later rotation block = left operand).
// X is identity on rows < ax; Y is identity on cols < ay.
__global__ __launch_bounds__(256) void combine_kernel(const float* __restrict__ src,
                                                      float* __restrict__ dst,
                                                      int srcCap, int dstCap,
                                                      int half, int R, int P) {
    const int side = blockIdx.z / P, m = blockIdx.z % P;
    const int bx = blockIdx.x & 7, by = blockIdx.x >> 3;
    const int row0 = by * 64, col0 = bx * 64;
    const float* __restrict__ X = src + ((size_t)(side * srcCap + 2 * m + 1)) * MAT;
    const float* __restrict__ Y = src + ((size_t)(side * srcCap + 2 * m)) * MAT;
    float* __restrict__ C = dst + ((size_t)(side * dstCap + m)) * MAT;
    const int ax = pivot_of((2 * m * half + half) * R);
    const int ay = pivot_of((2 * m * half) * R);
    const int tid = threadIdx.x;

    if (row0 + 64 <= ax) {                     // X rows identity -> C tile = Y tile
        for (int t = tid; t < 64 * 16; t += 256) {
            int r = t >> 4, q = (t & 15) * 4;
            size_t off = (size_t)(row0 + r) * NDIM + col0 + q;
            *(float4*)&C[off] = *(const float4*)&Y[off];
        }
        return;
    }
    if (col0 + 64 <= ay) {                     // Y cols identity -> C tile = X tile
        for (int t = tid; t < 64 * 16; t += 256) {
            int r = t >> 4, q = (t & 15) * 4;
            size_t off = (size_t)(row0 + r) * NDIM + col0 + q;
            *(float4*)&C[off] = *(const float4*)&X[off];
        }
        return;
    }

    __shared__ float Xs[64][36];
    __shared__ float Ys[32][68];
    const int tx = tid & 15, ty = tid >> 4;
    float acc[4][4] = {};
    // rows >= ax have X[r,k<ax] == 0 -> start K loop at ax (rounded down to 32)
    const int kt0 = (row0 >= ax) ? (ax >> 5) : 0;
    for (int kt = kt0; kt < 16; ++kt) {
        {
            int r = tid >> 2, q = (tid & 3) * 4;
            const float* xr = X + (size_t)(row0 + r) * NDIM + kt * 32;
            *(float4*)&Xs[r][q]      = *(const float4*)(xr + q);
            *(float4*)&Xs[r][q + 16] = *(const float4*)(xr + q + 16);
        }
        {
            int kk = tid >> 4, cq = (tid & 15) * 4;
            *(float4*)&Ys[kk][cq]      = *(const float4*)(Y + (size_t)(kt * 32 + kk) * NDIM + col0 + cq);
            *(float4*)&Ys[kk + 16][cq] = *(const float4*)(Y + (size_t)(kt * 32 + kk + 16) * NDIM + col0 + cq);
        }
        __syncthreads();
        #pragma unroll
        for (int kk = 0; kk < 32; ++kk) {
            float av[4] = {Xs[ty * 4 + 0][kk], Xs[ty * 4 + 1][kk],
                           Xs[ty * 4 + 2][kk], Xs[ty * 4 + 3][kk]};
            float4 B = *(const float4*)&Ys[kk][tx * 4];
            float bv[4] = {B.x, B.y, B.z, B.w};
            #pragma unroll
            for (int mm = 0; mm < 4; ++mm)
                #pragma unroll
                for (int nn = 0; nn < 4; ++nn)
                    acc[mm][nn] = fmaf(av[mm], bv[nn], acc[mm][nn]);
        }
        __syncthreads();
    }
    #pragma unroll
    for (int mm = 0; mm < 4; ++mm) {
        float4 st = make_float4(acc[mm][0], acc[mm][1], acc[mm][2], acc[mm][3]);
        *(float4*)&C[(size_t)(row0 + ty * 4 + mm) * NDIM + col0 + tx * 4] = st;
    }
}

// ---------------------------------------------------------------- W assembly
// W = diag(dU) * Ru * diag(sigma*dV) * Rv
__global__ __launch_bounds__(256) void wasm_kernel(const float* __restrict__ Ru,
                                                   const float* __restrict__ Rv,
                                                   const float* __restrict__ dU,
                                                   const float* __restrict__ dV,
                                                   const float* __restrict__ sg,
                                                   float* __restrict__ W) {
    const int bx = blockIdx.x & 7, by = blockIdx.x >> 3;
    const int row0 = by * 64, col0 = bx * 64;
    __shared__ float Xs[64][36];
    __shared__ float Ys[32][68];
    const int tid = threadIdx.x;
    const int tx = tid & 15, ty = tid >> 4;
    float acc[4][4] = {};
    for (int kt = 0; kt < 16; ++kt) {
        {
            int r = tid >> 2, q = (tid & 3) * 4;
            const float* xr = Ru + (size_t)(row0 + r) * NDIM + kt * 32;
            *(float4*)&Xs[r][q]      = *(const float4*)(xr + q);
            *(float4*)&Xs[r][q + 16] = *(const float4*)(xr + q + 16);
        }
        {
            int kk = tid >> 4, cq = (tid & 15) * 4;
            int kg = kt * 32 + kk;
            float sd = sg[kg] * dV[kg];
            float4 b = *(const float4*)(Rv + (size_t)kg * NDIM + col0 + cq);
            b.x *= sd; b.y *= sd; b.z *= sd; b.w *= sd;
            *(float4*)&Ys[kk][cq] = b;
            int kg2 = kg + 16;
            float sd2 = sg[kg2] * dV[kg2];
            float4 b2 = *(const float4*)(Rv + (size_t)kg2 * NDIM + col0 + cq);
            b2.x *= sd2; b2.y *= sd2; b2.z *= sd2; b2.w *= sd2;
            *(float4*)&Ys[kk + 16][cq] = b2;
        }
        __syncthreads();
        #pragma unroll
        for (int kk = 0; kk < 32; ++kk) {
            float av[4] = {Xs[ty * 4 + 0][kk], Xs[ty * 4 + 1][kk],
                           Xs[ty * 4 + 2][kk], Xs[ty * 4 + 3][kk]};
            float4 B = *(const float4*)&Ys[kk][tx * 4];
            float bv[4] = {B.x, B.y, B.z, B.w};
            #pragma unroll
            for (int mm = 0; mm < 4; ++mm)
                #pragma unroll
                for (int nn = 0; nn < 4; ++nn)
                    acc[mm][nn] = fmaf(av[mm], bv[nn], acc[mm][nn]);
        }
        __syncthreads();
    }
    #pragma unroll
    for (int mm = 0; mm < 4; ++mm) {
        float du = dU[row0 + ty * 4 + mm];
        float4 st = make_float4(acc[mm][0] * du, acc[mm][1] * du,
                                acc[mm][2] * du, acc[mm][3] * du);
        *(float4*)&W[(size_t)(row0 + ty * 4 + mm) * NDIM + col0 + tx * 4] = st;
    }
}

// ---------------------------------------------------------------- final GEMM
// out[t,o] = sum_i x[t,i] * W[o,i].  128x64 tile, BK=32, 8x4 micro-tile.
__global__ __launch_bounds__(256) void gemm_kernel(const float* __restrict__ x,
                                                   const float* __restrict__ W,
                                                   float* __restrict__ out) {
    const int col0 = blockIdx.x * 64;
    const int row0 = blockIdx.y * 128;
    __shared__ float Xs[32][132];   // [k][token]
    __shared__ float Ys[32][68];    // [k][outcol]
    const int tid = threadIdx.x;
    const int tx = tid & 15, ty = tid >> 4;
    float acc[8][4] = {};
    for (int kt = 0; kt < 16; ++kt) {
        {
            int r = tid & 127;
            int ks = (tid >> 7) * 16;
            const float* xr = x + (size_t)(row0 + r) * NDIM + kt * 32 + ks;
            #pragma unroll
            for (int u = 0; u < 4; ++u) {
                float4 vv = *(const float4*)(xr + u * 4);
                Xs[ks + u * 4 + 0][r] = vv.x;
                Xs[ks + u * 4 + 1][r] = vv.y;
                Xs[ks + u * 4 + 2][r] = vv.z;
                Xs[ks + u * 4 + 3][r] = vv.w;
            }
        }
        {
            int o = tid & 63;
            int ks = (tid >> 6) * 4;
            const float* wr = W + (size_t)(col0 + o) * NDIM + kt * 32;
            float4 w0 = *(const float4*)(wr + ks);
            float4 w1 = *(const float4*)(wr + ks + 16);
            Ys[ks + 0][o] = w0.x; Ys[ks + 1][o] = w0.y;
            Ys[ks + 2][o] = w0.z; Ys[ks + 3][o] = w0.w;
            Ys[ks + 16][o] = w1.x; Ys[ks + 17][o] = w1.y;
            Ys[ks + 18][o] = w1.z; Ys[ks + 19][o] = w1.w;
        }
        __syncthreads();
        #pragma unroll
        for (int kk = 0; kk < 32; ++kk) {
            float4 A0 = *(const float4*)&Xs[kk][ty * 8];
            float4 A1 = *(const float4*)&Xs[kk][ty * 8 + 4];
            float4 B  = *(const float4*)&Ys[kk][tx * 4];
            float av[8] = {A0.x, A0.y, A0.z, A0.w, A1.x, A1.y, A1.z, A1.w};
            float bv[4] = {B.x, B.y, B.z, B.w};
            #pragma unroll
            for (int mm = 0; mm < 8; ++mm)
                #pragma unroll
                for (int nn = 0; nn < 4; ++nn)
                    acc[mm][nn] = fmaf(av[mm], bv[nn], acc[mm][nn]);
        }
        __syncthreads();
    }
    #pragma unroll
    for (int mm = 0; mm < 8; ++mm) {
        float4 st = make_float4(acc[mm][0], acc[mm][1], acc[mm][2], acc[mm][3]);
        *(float4*)&out[(size_t)(row0 + ty * 8 + mm) * NDIM + col0 + tx * 4] = st;
    }
}

// ---------------------------------------------------------------- host
extern "C" void kernel_launch(void* const* d_in, const int* in_sizes, int n_in,
                              void* d_out, int out_size, void* d_ws, size_t ws_size,
                              hipStream_t stream) {
    (void)in_sizes; (void)n_in; (void)out_size;
    const float* xp   = (const float*)d_in[0];
    const float* phiU = (const float*)d_in[1];
    const float* dUp  = (const float*)d_in[2];
    const float* phiV = (const float*)d_in[3];
    const float* dVp  = (const float*)d_in[4];
    const float* sgp  = (const float*)d_in[5];
    float* out = (float*)d_out;
    float* wsf = (float*)d_ws;

    // Pick largest G (rotation blocks per matrix) that fits the workspace.
    int G = 16;
    while (G > 1) {
        size_t needFloats = (size_t)4 * NPAIR + (size_t)2 * G * MAT
                          + (size_t)G * MAT + MAT;
        if (needFloats * 4 <= ws_size) break;
        G >>= 1;
    }
    const int R = NPAIR / G;   // exact for G in {1,2,4,8,16}

    float2* csU = (float2*)wsf;
    float2* csV = csU + NPAIR;
    float* bufA = wsf + (size_t)4 * NPAIR;
    float* bufB = bufA + (size_t)2 * G * MAT;
    const int capB = (G > 1) ? G / 2 : 1;
    float* Wbuf = (G > 1) ? (bufB + (size_t)2 * capB * MAT) : bufB;

    // 1) trig
    trig_kernel<<<dim3((2 * NPAIR + 255) / 256), 256, 0, stream>>>(phiU, phiV, csU, csV);

    // 2) block products (both sides in one launch)
    group_kernel<<<dim3(16, G, 2), 64, 0, stream>>>(csU, csV, bufA, R, G);

    // 3) tree combine: log2(G) rounds, ping-pong bufA <-> bufB
    const float* cur = bufA;
    float* oth = bufB;
    int curCap = G, othCap = capB;
    for (int P = G / 2, half = 1; P >= 1; P >>= 1, half <<= 1) {
        combine_kernel<<<dim3(64, 1, 2 * P), 256, 0, stream>>>(cur, oth, curCap, othCap, half, R, P);
        const float* t = cur; cur = oth; oth = (float*)t;
        int tc = curCap; curCap = othCap; othCap = tc;
    }
    const float* Ru = cur;
    const float* Rv = cur + (size_t)curCap * MAT;

    // 4) W assembly
    wasm_kernel<<<dim3(64), 256, 0, stream>>>(Ru, Rv, dUp, dVp, sgp, Wbuf);

    // 5) out = x * W^T
    gemm_kernel<<<dim3(8, 256), 256, 0, stream>>>(xp, Wbuf, out);
}

// Round 5
// 843.862 us; speedup vs baseline: 1.6400x; 1.1292x over previous
//
#include <hip/hip_runtime.h>
#include <cmath>

// MZILinear: out = x @ W^T, W = diag(dU)*Ru*diag(sigma*dV)*Rv,
// Ru/Rv = product of 130816 Givens rotations (Reck order) applied to I.
//
// Pipeline:
//  1) trig_kernel  : (c,s) pairs for both phi arrays
//  2) group_kernel : split rotation sequence into G contiguous blocks, build
//                    each block product from identity. v4: (c,s) staged into
//                    LDS in chunks so the fan loop is PURE-DS.  v3 read cs via
//                    wave-uniform global loads -> s_load (SMEM); SMEM+DS mix
//                    forces lgkmcnt(0) per rotation (out-of-order completion),
//                    draining the prefetch ring -> 139 cyc/rot.  Pure-DS gets
//                    counted lgkmcnt waits, so the 8-deep ring actually hides
//                    the ~120-cyc LDS latency.
//  3) combine_kernel (log2 G rounds): tree-multiply block products
//  4) wasm_kernel  : W = diag(dU) * Ru * diag(sigma*dV) * Rv
//  5) gemm_kernel  : out[32768,512] = x * W^T (fp32 VALU, 128x64 tile)

#define NDIM 512
#define NPAIR 130816            // 512*511/2
#define MAT (NDIM * NDIM)       // 262144 floats per matrix slot
#define CSCHUNK 1024            // rotations staged per LDS chunk (8 KiB)

// T(i) = number of rotations before pivot i starts = i*(1023-i)/2
__device__ __forceinline__ int T_of(int i) { return (i * (1023 - i)) >> 1; }

// largest i with T(i) <= k
__device__ __forceinline__ int pivot_of(int k) {
    int lo = 0, hi = 511;
    while (lo < hi) {
        int mid = (lo + hi + 1) >> 1;
        if (T_of(mid) <= k) lo = mid; else hi = mid - 1;
    }
    return lo;
}

// ---------------------------------------------------------------- trig
__global__ __launch_bounds__(256) void trig_kernel(const float* __restrict__ pU,
                                                   const float* __restrict__ pV,
                                                   float2* __restrict__ csU,
                                                   float2* __restrict__ csV) {
    int idx = blockIdx.x * 256 + threadIdx.x;
    if (idx < NPAIR) {
        float s, c;
        sincosf(pU[idx], &s, &c);
        csU[idx] = make_float2(c, s);
    } else if (idx < 2 * NPAIR) {
        int m = idx - NPAIR;
        float s, c;
        sincosf(pV[m], &s, &c);
        csV[m] = make_float2(c, s);
    }
}

// ---------------------------------------------------------------- group products
// One wave per block, 32 active lanes = 32 columns; state v[row][lane] in LDS.
// Per pivot i, rotations sweep rows j = hi..i+1.  Only the pivot-row value vi
// chains serially (2 dependent FMAs/rot); vj reads are independent rows and
// are prefetched 8 deep.  cs pairs come from the LDS chunk buffer (pure DS).
__global__ __launch_bounds__(64) void group_kernel(const float2* __restrict__ csU,
                                                   const float2* __restrict__ csV,
                                                   float* __restrict__ bufA,
                                                   int R, int capA) {
    __shared__ float v[NDIM * 32];
    __shared__ float2 csl[CSCHUNK];
    const int lane = threadIdx.x;
    if (lane >= 32) return;                    // half-wave active; no barriers used
    const int col0 = blockIdx.x * 32;
    const int col  = col0 + lane;
    const int g    = blockIdx.y;
    const int side = blockIdx.z;               // 0 = U, 1 = V
    const int k0 = g * R, k1 = k0 + R;
    const int i0 = pivot_of(k0);
    float* out = bufA + ((size_t)(side * capA + g)) * MAT;

    if (col0 + 32 <= i0) {                     // columns < first pivot: identity
        for (int r = 0; r < NDIM; ++r)
            out[(size_t)r * NDIM + col] = (r == col) ? 1.f : 0.f;
        return;
    }
    const float2* __restrict__ csp = side ? csV : csU;

    for (int r = 0; r < NDIM; ++r)             // column state = e_col
        v[r * 32 + lane] = (r == col) ? 1.f : 0.f;

    int i = i0;
    int j = 511 - (k0 - T_of(i0));
    int k = k0;

    for (int kc = k0; kc < k1 && i < 511; kc += CSCHUNK) {
        const int kcEnd = (k1 < kc + CSCHUNK) ? k1 : (kc + CSCHUNK);

        // stage (c,s)[kc..kcEnd) into LDS: per-lane vector global loads
        for (int t = lane; t < kcEnd - kc; t += 32)
            csl[t] = csp[kc + t];
        // single wave: ds-write -> ds-read ordering is program order (in-order
        // DS pipe); compiler inserts the lgkmcnt wait.

        while (k < kcEnd && i < 511) {
            float vi = v[i * 32 + lane];
            const int cnt = min(kcEnd - k, j - i);   // rotations this segment
            const int kb = k - kc;                   // base offset in csl
            float2 csb[8], csc[8];
            float  vjb[8], vjc[8];

            // prologue: fill ring with t = 0..7
            #pragma unroll
            for (int u = 0; u < 8; ++u) {
                if (u < cnt) {
                    csb[u] = csl[kb + u];
                    vjb[u] = v[(j - u) * 32 + lane];
                }
            }

            // main: t in [0, nf8), always 8-deep prefetch. nf8 = multiple of 8.
            const int nf8 = (cnt > 8) ? ((cnt - 8) & ~7) : 0;
            for (int tb = 0; tb < nf8; tb += 8) {
                #pragma unroll
                for (int u = 0; u < 8; ++u) {
                    const int t = tb + u;
                    const float c = csb[u].x, s = csb[u].y, vj = vjb[u];
                    csb[u] = csl[kb + t + 8];                // in-bounds: t+8 < cnt
                    vjb[u] = v[(j - t - 8) * 32 + lane];     // row >= i+1
                    const float vjn = fmaf(s, vi, c * vj);
                    vi = fmaf(c, vi, -(s * vj));
                    v[(j - t) * 32 + lane] = vjn;
                }
            }

            // epilogue A: consume t = nf8+u, prefetch t+8 into second ring
            #pragma unroll
            for (int u = 0; u < 8; ++u) {
                const int t = nf8 + u;
                if (t < cnt) {
                    const float c = csb[u].x, s = csb[u].y, vj = vjb[u];
                    if (t + 8 < cnt) {
                        csc[u] = csl[kb + t + 8];
                        vjc[u] = v[(j - t - 8) * 32 + lane];
                    }
                    const float vjn = fmaf(s, vi, c * vj);
                    vi = fmaf(c, vi, -(s * vj));
                    v[(j - t) * 32 + lane] = vjn;
                }
            }
            // epilogue B: consume second ring, t = nf8+8+u  (cnt - nf8 <= 15)
            #pragma unroll
            for (int u = 0; u < 8; ++u) {
                const int t = nf8 + 8 + u;
                if (t < cnt) {
                    const float c = csc[u].x, s = csc[u].y, vj = vjc[u];
                    const float vjn = fmaf(s, vi, c * vj);
                    vi = fmaf(c, vi, -(s * vj));
                    v[(j - t) * 32 + lane] = vjn;
                }
            }

            k += cnt; j -= cnt;
            v[i * 32 + lane] = vi;
            if (j == i) { ++i; j = 511; }
        }
    }

    for (int r = 0; r < NDIM; ++r)
        out[(size_t)r * NDIM + col] = v[r * 32 + lane];
}

// ---------------------------------------------------------------- combine rounds
// C[m] = src[2m+1] * src[2m]  (X = later rotation block = left operand).
// X is identity on rows < ax; Y is identity on cols < ay.
__global__ __launch_bounds__(256) void combine_kernel(const float* __restrict__ src,
                                                      float* __restrict__ dst,
                                                      int srcCap, int dstCap,
                                                      int half, int R, int P) {
    const int side = blockIdx.z / P, m = blockIdx.z % P;
    const int bx = blockIdx.x & 7, by = blockIdx.x >> 3;
    const int row0 = by * 64, col0 = bx * 64;
    const float* __restrict__ X = src + ((size_t)(side * srcCap + 2 * m + 1)) * MAT;
    const float* __restrict__ Y = src + ((size_t)(side * srcCap + 2 * m)) * MAT;
    float* __restrict__ C = dst + ((size_t)(side * dstCap + m)) * MAT;
    const int ax = pivot_of((2 * m * half + half) * R);
    const int ay = pivot_of((2 * m * half) * R);
    const int tid = threadIdx.x;

    if (row0 + 64 <= ax) {                     // X rows identity -> C tile = Y tile
        for (int t = tid; t < 64 * 16; t += 256) {
            int r = t >> 4, q = (t & 15) * 4;
            size_t off = (size_t)(row0 + r) * NDIM + col0 + q;
            *(float4*)&C[off] = *(const float4*)&Y[off];
        }
        return;
    }
    if (col0 + 64 <= ay) {                     // Y cols identity -> C tile = X tile
        for (int t = tid; t < 64 * 16; t += 256) {
            int r = t >> 4, q = (t & 15) * 4;
            size_t off = (size_t)(row0 + r) * NDIM + col0 + q;
            *(float4*)&C[off] = *(const float4*)&X[off];
        }
        return;
    }

    __shared__ float Xs[64][36];
    __shared__ float Ys[32][68];
    const int tx = tid & 15, ty = tid >> 4;
    float acc[4][4] = {};
    // rows >= ax have X[r,k<ax] == 0 -> start K loop at ax (rounded down to 32)
    const int kt0 = (row0 >= ax) ? (ax >> 5) : 0;
    for (int kt = kt0; kt < 16; ++kt) {
        {
            int r = tid >> 2, q = (tid & 3) * 4;
            const float* xr = X + (size_t)(row0 + r) * NDIM + kt * 32;
            *(float4*)&Xs[r][q]      = *(const float4*)(xr + q);
            *(float4*)&Xs[r][q + 16] = *(const float4*)(xr + q + 16);
        }
        {
            int kk = tid >> 4, cq = (tid & 15) * 4;
            *(float4*)&Ys[kk][cq]      = *(const float4*)(Y + (size_t)(kt * 32 + kk) * NDIM + col0 + cq);
            *(float4*)&Ys[kk + 16][cq] = *(const float4*)(Y + (size_t)(kt * 32 + kk + 16) * NDIM + col0 + cq);
        }
        __syncthreads();
        #pragma unroll
        for (int kk = 0; kk < 32; ++kk) {
            float av[4] = {Xs[ty * 4 + 0][kk], Xs[ty * 4 + 1][kk],
                           Xs[ty * 4 + 2][kk], Xs[ty * 4 + 3][kk]};
            float4 B = *(const float4*)&Ys[kk][tx * 4];
            float bv[4] = {B.x, B.y, B.z, B.w};
            #pragma unroll
            for (int mm = 0; mm < 4; ++mm)
                #pragma unroll
                for (int nn = 0; nn < 4; ++nn)
                    acc[mm][nn] = fmaf(av[mm], bv[nn], acc[mm][nn]);
        }
        __syncthreads();
    }
    #pragma unroll
    for (int mm = 0; mm < 4; ++mm) {
        float4 st = make_float4(acc[mm][0], acc[mm][1], acc[mm][2], acc[mm][3]);
        *(float4*)&C[(size_t)(row0 + ty * 4 + mm) * NDIM + col0 + tx * 4] = st;
    }
}

// ---------------------------------------------------------------- W assembly
// W = diag(dU) * Ru * diag(sigma*dV) * Rv
__global__ __launch_bounds__(256) void wasm_kernel(const float* __restrict__ Ru,
                                                   const float* __restrict__ Rv,
                                                   const float* __restrict__ dU,
                                                   const float* __restrict__ dV,
                                                   const float* __restrict__ sg,
                                                   float* __restrict__ W) {
    const int bx = blockIdx.x & 7, by = blockIdx.x >> 3;
    const int row0 = by * 64, col0 = bx * 64;
    __shared__ float Xs[64][36];
    __shared__ float Ys[32][68];
    const int tid = threadIdx.x;
    const int tx = tid & 15, ty = tid >> 4;
    float acc[4][4] = {};
    for (int kt = 0; kt < 16; ++kt) {
        {
            int r = tid >> 2, q = (tid & 3) * 4;
            const float* xr = Ru + (size_t)(row0 + r) * NDIM + kt * 32;
            *(float4*)&Xs[r][q]      = *(const float4*)(xr + q);
            *(float4*)&Xs[r][q + 16] = *(const float4*)(xr + q + 16);
        }
        {
            int kk = tid >> 4, cq = (tid & 15) * 4;
            int kg = kt * 32 + kk;
            float sd = sg[kg] * dV[kg];
            float4 b = *(const float4*)(Rv + (size_t)kg * NDIM + col0 + cq);
            b.x *= sd; b.y *= sd; b.z *= sd; b.w *= sd;
            *(float4*)&Ys[kk][cq] = b;
            int kg2 = kg + 16;
            float sd2 = sg[kg2] * dV[kg2];
            float4 b2 = *(const float4*)(Rv + (size_t)kg2 * NDIM + col0 + cq);
            b2.x *= sd2; b2.y *= sd2; b2.z *= sd2; b2.w *= sd2;
            *(float4*)&Ys[kk + 16][cq] = b2;
        }
        __syncthreads();
        #pragma unroll
        for (int kk = 0; kk < 32; ++kk) {
            float av[4] = {Xs[ty * 4 + 0][kk], Xs[ty * 4 + 1][kk],
                           Xs[ty * 4 + 2][kk], Xs[ty * 4 + 3][kk]};
            float4 B = *(const float4*)&Ys[kk][tx * 4];
            float bv[4] = {B.x, B.y, B.z, B.w};
            #pragma unroll
            for (int mm = 0; mm < 4; ++mm)
                #pragma unroll
                for (int nn = 0; nn < 4; ++nn)
                    acc[mm][nn] = fmaf(av[mm], bv[nn], acc[mm][nn]);
        }
        __syncthreads();
    }
    #pragma unroll
    for (int mm = 0; mm < 4; ++mm) {
        float du = dU[row0 + ty * 4 + mm];
        float4 st = make_float4(acc[mm][0] * du, acc[mm][1] * du,
                                acc[mm][2] * du, acc[mm][3] * du);
        *(float4*)&W[(size_t)(row0 + ty * 4 + mm) * NDIM + col0 + tx * 4] = st;
    }
}

// ---------------------------------------------------------------- final GEMM
// out[t,o] = sum_i x[t,i] * W[o,i].  128x64 tile, BK=32, 8x4 micro-tile.
__global__ __launch_bounds__(256) void gemm_kernel(const float* __restrict__ x,
                                                   const float* __restrict__ W,
                                                   float* __restrict__ out) {
    const int col0 = blockIdx.x * 64;
    const int row0 = blockIdx.y * 128;
    __shared__ float Xs[32][132];   // [k][token]
    __shared__ float Ys[32][68];    // [k][outcol]
    const int tid = threadIdx.x;
    const int tx = tid & 15, ty = tid >> 4;
    float acc[8][4] = {};
    for (int kt = 0; kt < 16; ++kt) {
        {
            int r = tid & 127;
            int ks = (tid >> 7) * 16;
            const float* xr = x + (size_t)(row0 + r) * NDIM + kt * 32 + ks;
            #pragma unroll
            for (int u = 0; u < 4; ++u) {
                float4 vv = *(const float4*)(xr + u * 4);
                Xs[ks + u * 4 + 0][r] = vv.x;
                Xs[ks + u * 4 + 1][r] = vv.y;
                Xs[ks + u * 4 + 2][r] = vv.z;
                Xs[ks + u * 4 + 3][r] = vv.w;
            }
        }
        {
            int o = tid & 63;
            int ks = (tid >> 6) * 4;
            const float* wr = W + (size_t)(col0 + o) * NDIM + kt * 32;
            float4 w0 = *(const float4*)(wr + ks);
            float4 w1 = *(const float4*)(wr + ks + 16);
            Ys[ks + 0][o] = w0.x; Ys[ks + 1][o] = w0.y;
            Ys[ks + 2][o] = w0.z; Ys[ks + 3][o] = w0.w;
            Ys[ks + 16][o] = w1.x; Ys[ks + 17][o] = w1.y;
            Ys[ks + 18][o] = w1.z; Ys[ks + 19][o] = w1.w;
        }
        __syncthreads();
        #pragma unroll
        for (int kk = 0; kk < 32; ++kk) {
            float4 A0 = *(const float4*)&Xs[kk][ty * 8];
            float4 A1 = *(const float4*)&Xs[kk][ty * 8 + 4];
            float4 B  = *(const float4*)&Ys[kk][tx * 4];
            float av[8] = {A0.x, A0.y, A0.z, A0.w, A1.x, A1.y, A1.z, A1.w};
            float bv[4] = {B.x, B.y, B.z, B.w};
            #pragma unroll
            for (int mm = 0; mm < 8; ++mm)
                #pragma unroll
                for (int nn = 0; nn < 4; ++nn)
                    acc[mm][nn] = fmaf(av[mm], bv[nn], acc[mm][nn]);
        }
        __syncthreads();
    }
    #pragma unroll
    for (int mm = 0; mm < 8; ++mm) {
        float4 st = make_float4(acc[mm][0], acc[mm][1], acc[mm][2], acc[mm][3]);
        *(float4*)&out[(size_t)(row0 + ty * 8 + mm) * NDIM + col0 + tx * 4] = st;
    }
}

// ---------------------------------------------------------------- host
extern "C" void kernel_launch(void* const* d_in, const int* in_sizes, int n_in,
                              void* d_out, int out_size, void* d_ws, size_t ws_size,
                              hipStream_t stream) {
    (void)in_sizes; (void)n_in; (void)out_size;
    const float* xp   = (const float*)d_in[0];
    const float* phiU = (const float*)d_in[1];
    const float* dUp  = (const float*)d_in[2];
    const float* phiV = (const float*)d_in[3];
    const float* dVp  = (const float*)d_in[4];
    const float* sgp  = (const float*)d_in[5];
    float* out = (float*)d_out;
    float* wsf = (float*)d_ws;

    // Pick largest G (rotation blocks per matrix) that fits the workspace.
    int G = 16;
    while (G > 1) {
        size_t needFloats = (size_t)4 * NPAIR + (size_t)2 * G * MAT
                          + (size_t)G * MAT + MAT;
        if (needFloats * 4 <= ws_size) break;
        G >>= 1;
    }
    const int R = NPAIR / G;   // exact for G in {1,2,4,8,16}

    float2* csU = (float2*)wsf;
    float2* csV = csU + NPAIR;
    float* bufA = wsf + (size_t)4 * NPAIR;
    float* bufB = bufA + (size_t)2 * G * MAT;
    const int capB = (G > 1) ? G / 2 : 1;
    float* Wbuf = (G > 1) ? (bufB + (size_t)2 * capB * MAT) : bufB;

    // 1) trig
    trig_kernel<<<dim3((2 * NPAIR + 255) / 256), 256, 0, stream>>>(phiU, phiV, csU, csV);

    // 2) block products (both sides in one launch)
    group_kernel<<<dim3(16, G, 2), 64, 0, stream>>>(csU, csV, bufA, R, G);

    // 3) tree combine: log2(G) rounds, ping-pong bufA <-> bufB
    const float* cur = bufA;
    float* oth = bufB;
    int curCap = G, othCap = capB;
    for (int P = G / 2, half = 1; P >= 1; P >>= 1, half <<= 1) {
        combine_kernel<<<dim3(64, 1, 2 * P), 256, 0, stream>>>(cur, oth, curCap, othCap, half, R, P);
        const float* t = cur; cur = oth; oth = (float*)t;
        int tc = curCap; curCap = othCap; othCap = tc;
    }
    const float* Ru = cur;
    const float* Rv = cur + (size_t)curCap * MAT;

    // 4) W assembly
    wasm_kernel<<<dim3(64), 256, 0, stream>>>(Ru, Rv, dUp, dVp, sgp, Wbuf);

    // 5) out = x * W^T
    gemm_kernel<<<dim3(8, 256), 256, 0, stream>>>(xp, Wbuf, out);
}

// Round 6
// 814.247 us; speedup vs baseline: 1.6996x; 1.0364x over previous
//
#include <hip/hip_runtime.h>
#include <cmath>

// MZILinear: out = x @ W^T, W = diag(dU)*Ru*diag(sigma*dV)*Rv,
// Ru/Rv = product of 130816 Givens rotations (Reck order) applied to I.
//
// Pipeline:
//  1) trig_kernel  : (c,s) pairs, written in a FAN-PADDED layout (each pivot
//                    fan's cs starts 16B-aligned; pads are identity (1,0))
//  2) group_kernel : G contiguous rotation blocks -> block products from I.
//                    v5: 32-rotation row-tiles. Fan rotation t maps to row
//                    511-t, so 32 consecutive rows = 32 consecutive cs slots.
//                    Bulk ds_read_b64 the rows + uniform b128 the cs, rotate
//                    fully in registers, bulk write back. LDS latency is paid
//                    per-tile (amortized /32), not per-rotation (v1-v4 all
//                    measured ~113-139 cyc/rot = one LDS round trip each).
//                    Partial tiles use (c,s)=(1,0) clamps (identity rotations
//                    write back unchanged values - harmless).
//  3) combine_kernel (log2 G rounds): tree-multiply block products
//  4) wasm_kernel  : W = diag(dU) * Ru * diag(sigma*dV) * Rv
//  5) gemm_kernel  : out[32768,512] = x * W^T (fp32 VALU, 128x64 tile)

#define NDIM 512
#define NPAIR 130816            // 512*511/2
#define MAT (NDIM * NDIM)       // 262144 floats per matrix slot
#define VSTRIDE 514             // per-lane state stride: banks (2l+r)%32, 2-way=free
#define PCAP 131584             // padded cs slots = base_of(511)
#define PSLACK 520
#define PTOT (PCAP + PSLACK)

// T(i) = number of rotations before pivot i starts = i*(1023-i)/2
__device__ __forceinline__ int T_of(int i) { return (i * (1023 - i)) >> 1; }

// fan-padded base: base(i) = T(i) + 6*(i/4) + {0,1,3,6}[i%4]  (16B aligned)
__device__ __forceinline__ int base_of(int i) {
    return T_of(i) + 6 * (i >> 2) + ((0x6310 >> ((i & 3) * 4)) & 0xF);
}

// largest i with T(i) <= k
__device__ __forceinline__ int pivot_of(int k) {
    int lo = 0, hi = 511;
    while (lo < hi) {
        int mid = (lo + hi + 1) >> 1;
        if (T_of(mid) <= k) lo = mid; else hi = mid - 1;
    }
    return lo;
}

// ---------------------------------------------------------------- trig
// Fills the fan-padded (c,s) arrays; pad slots get identity (1,0).
__global__ __launch_bounds__(256) void trig_kernel(const float* __restrict__ pU,
                                                   const float* __restrict__ pV,
                                                   float2* __restrict__ csU,
                                                   float2* __restrict__ csV) {
    int idx = blockIdx.x * 256 + threadIdx.x;
    if (idx >= 2 * PTOT) return;
    const int side = idx >= PTOT;
    const int s = idx - side * PTOT;
    const float* __restrict__ phi = side ? pV : pU;
    float2* __restrict__ dst = side ? csV : csU;
    int lo = 0, hi = 510;                      // largest i with base(i) <= s
    while (lo < hi) {
        int mid = (lo + hi + 1) >> 1;
        if (base_of(mid) <= s) lo = mid; else hi = mid - 1;
    }
    const int i = lo, t = s - base_of(i), L = 511 - i;
    float2 cs = make_float2(1.f, 0.f);
    if (t < L) {
        float sn, cn;
        sincosf(phi[T_of(i) + t], &sn, &cn);
        cs = make_float2(cn, sn);
    }
    dst[s] = cs;
}

// ---------------------------------------------------------------- group products
// One wave per block, 32 active lanes = 32 columns. State: vs[lane*514 + row].
// Rotation step (p=i, q=j): U[q]=s*rp+c*rq ; U[p]=c*rp-s*rq. vi = running
// pivot-row value (register). Tiles of 32 rows descending; u-th rotation in a
// tile handles row rb31-u and cs slot 480-32b+u of the fan.
#define DR(WREF, CC, SS) { const float vj_ = (WREF); const float cx_ = (CC), sx_ = (SS); \
    (WREF) = fmaf(sx_, vi, cx_ * vj_); vi = fmaf(cx_, vi, -(sx_ * vj_)); }

#define R2(A) \
    DR(w2[15-(A)].y, c4[(A)].x, c4[(A)].y) \
    DR(w2[15-(A)].x, c4[(A)].z, c4[(A)].w)

#define GP(A) { \
    { const int rr = rb31 - 2*(A);     if (rr < rLo || rr > rHi) { c4[(A)].x = 1.f; c4[(A)].y = 0.f; } } \
    { const int rr = rb31 - 2*(A) - 1; if (rr < rLo || rr > rHi) { c4[(A)].z = 1.f; c4[(A)].w = 0.f; } } }

__global__ __launch_bounds__(64) void group_kernel(const float2* __restrict__ csU,
                                                   const float2* __restrict__ csV,
                                                   float* __restrict__ bufA,
                                                   int R, int capA) {
    __shared__ float vs[32 * VSTRIDE];
    __shared__ float2 csl[512];
    const int lane = threadIdx.x;
    if (lane >= 32) return;                    // half-wave active; no barriers used
    const int col0 = blockIdx.x * 32;
    const int col  = col0 + lane;
    const int g    = blockIdx.y;
    const int side = blockIdx.z;               // 0 = U, 1 = V
    const int k0 = g * R, k1 = k0 + R;
    const int i0 = pivot_of(k0);
    const int e0 = k0 - T_of(i0);
    float* out = bufA + ((size_t)(side * capA + g)) * MAT;

    if (col0 + 32 <= i0) {                     // columns < first pivot: identity
        for (int r = 0; r < NDIM; ++r)
            out[(size_t)r * NDIM + col] = (r == col) ? 1.f : 0.f;
        return;
    }
    const float2* __restrict__ pcs = side ? csV : csU;
    const int vb = lane * VSTRIDE;

    {                                          // column state = e_col
        const float2 z2 = make_float2(0.f, 0.f);
        for (int r = 0; r < NDIM; r += 2)
            *(float2*)&vs[vb + r] = z2;
        vs[vb + col] = 1.f;
    }

    int i = i0, k = k0;
    while (k < k1 && i < 511) {
        const int L = 511 - i;
        const int tStart = (i == i0) ? e0 : 0;
        const int tEnd = min(L, tStart + (k1 - k));
        const int rHi = 511 - tStart;          // first rotated row (inclusive)
        const int rLo = 512 - tEnd;            // last rotated row (inclusive)
        const int bHi = rHi >> 5, bLo = rLo >> 5;
        const int sBase = 480 - 32 * bHi;      // fan-relative slot of tile bHi's u=0
        const int sCount = 32 * (bHi - bLo + 1);

        // stage this fan's cs tile range into LDS (slots sBase .. sBase+sCount)
        {
            const float2* __restrict__ src = pcs + base_of(i) + sBase;
            #pragma unroll 4
            for (int t = lane; t < sCount; t += 32)
                csl[t] = src[t];
        }

        float vi = vs[vb + i];
        for (int b = bHi; b >= bLo; --b) {
            const int sT = 480 - 32 * b - sBase;
            const int rb31 = 32 * b + 31;
            float4 c4[16];
            float2 w2[16];
            #pragma unroll
            for (int m = 0; m < 16; ++m)
                c4[m] = *(const float4*)&csl[sT + 2 * m];
            #pragma unroll
            for (int m = 0; m < 16; ++m)
                w2[m] = *(const float2*)&vs[vb + 32 * b + 2 * m];

            if (32 * b < rLo || rb31 > rHi) {  // partial tile: clamp cs to identity
                GP(0)  GP(1)  GP(2)  GP(3)  GP(4)  GP(5)  GP(6)  GP(7)
                GP(8)  GP(9)  GP(10) GP(11) GP(12) GP(13) GP(14) GP(15)
            }
            R2(0)  R2(1)  R2(2)  R2(3)  R2(4)  R2(5)  R2(6)  R2(7)
            R2(8)  R2(9)  R2(10) R2(11) R2(12) R2(13) R2(14) R2(15)

            #pragma unroll
            for (int m = 0; m < 16; ++m)
                *(float2*)&vs[vb + 32 * b + 2 * m] = w2[m];
        }
        vs[vb + i] = vi;
        k += tEnd - tStart;
        ++i;
    }

    for (int r = 0; r < NDIM; ++r)
        out[(size_t)r * NDIM + col] = vs[vb + r];
}

// ---------------------------------------------------------------- combine rounds
// C[m] = src[2m+1] * src[2m]  (X = later rotation block = left operand).
// X is identity on rows < ax; Y is identity on cols < ay.
__global__ __launch_bounds__(256) void combine_kernel(const float* __restrict__ src,
                                                      float* __restrict__ dst,
                                                      int srcCap, int dstCap,
                                                      int half, int R, int P) {
    const int side = blockIdx.z / P, m = blockIdx.z % P;
    const int bx = blockIdx.x & 7, by = blockIdx.x >> 3;
    const int row0 = by * 64, col0 = bx * 64;
    const float* __restrict__ X = src + ((size_t)(side * srcCap + 2 * m + 1)) * MAT;
    const float* __restrict__ Y = src + ((size_t)(side * srcCap + 2 * m)) * MAT;
    float* __restrict__ C = dst + ((size_t)(side * dstCap + m)) * MAT;
    const int ax = pivot_of((2 * m * half + half) * R);
    const int ay = pivot_of((2 * m * half) * R);
    const int tid = threadIdx.x;

    if (row0 + 64 <= ax) {                     // X rows identity -> C tile = Y tile
        for (int t = tid; t < 64 * 16; t += 256) {
            int r = t >> 4, q = (t & 15) * 4;
            size_t off = (size_t)(row0 + r) * NDIM + col0 + q;
            *(float4*)&C[off] = *(const float4*)&Y[off];
        }
        return;
    }
    if (col0 + 64 <= ay) {                     // Y cols identity -> C tile = X tile
        for (int t = tid; t < 64 * 16; t += 256) {
            int r = t >> 4, q = (t & 15) * 4;
            size_t off = (size_t)(row0 + r) * NDIM + col0 + q;
            *(float4*)&C[off] = *(const float4*)&X[off];
        }
        return;
    }

    __shared__ float Xs[64][36];
    __shared__ float Ys[32][68];
    const int tx = tid & 15, ty = tid >> 4;
    float acc[4][4] = {};
    // rows >= ax have X[r,k<ax] == 0 -> start K loop at ax (rounded down to 32)
    const int kt0 = (row0 >= ax) ? (ax >> 5) : 0;
    for (int kt = kt0; kt < 16; ++kt) {
        {
            int r = tid >> 2, q = (tid & 3) * 4;
            const float* xr = X + (size_t)(row0 + r) * NDIM + kt * 32;
            *(float4*)&Xs[r][q]      = *(const float4*)(xr + q);
            *(float4*)&Xs[r][q + 16] = *(const float4*)(xr + q + 16);
        }
        {
            int kk = tid >> 4, cq = (tid & 15) * 4;
            *(float4*)&Ys[kk][cq]      = *(const float4*)(Y + (size_t)(kt * 32 + kk) * NDIM + col0 + cq);
            *(float4*)&Ys[kk + 16][cq] = *(const float4*)(Y + (size_t)(kt * 32 + kk + 16) * NDIM + col0 + cq);
        }
        __syncthreads();
        #pragma unroll
        for (int kk = 0; kk < 32; ++kk) {
            float av[4] = {Xs[ty * 4 + 0][kk], Xs[ty * 4 + 1][kk],
                           Xs[ty * 4 + 2][kk], Xs[ty * 4 + 3][kk]};
            float4 B = *(const float4*)&Ys[kk][tx * 4];
            float bv[4] = {B.x, B.y, B.z, B.w};
            #pragma unroll
            for (int mm = 0; mm < 4; ++mm)
                #pragma unroll
                for (int nn = 0; nn < 4; ++nn)
                    acc[mm][nn] = fmaf(av[mm], bv[nn], acc[mm][nn]);
        }
        __syncthreads();
    }
    #pragma unroll
    for (int mm = 0; mm < 4; ++mm) {
        float4 st = make_float4(acc[mm][0], acc[mm][1], acc[mm][2], acc[mm][3]);
        *(float4*)&C[(size_t)(row0 + ty * 4 + mm) * NDIM + col0 + tx * 4] = st;
    }
}

// ---------------------------------------------------------------- W assembly
// W = diag(dU) * Ru * diag(sigma*dV) * Rv
__global__ __launch_bounds__(256) void wasm_kernel(const float* __restrict__ Ru,
                                                   const float* __restrict__ Rv,
                                                   const float* __restrict__ dU,
                                                   const float* __restrict__ dV,
                                                   const float* __restrict__ sg,
                                                   float* __restrict__ W) {
    const int bx = blockIdx.x & 7, by = blockIdx.x >> 3;
    const int row0 = by * 64, col0 = bx * 64;
    __shared__ float Xs[64][36];
    __shared__ float Ys[32][68];
    const int tid = threadIdx.x;
    const int tx = tid & 15, ty = tid >> 4;
    float acc[4][4] = {};
    for (int kt = 0; kt < 16; ++kt) {
        {
            int r = tid >> 2, q = (tid & 3) * 4;
            const float* xr = Ru + (size_t)(row0 + r) * NDIM + kt * 32;
            *(float4*)&Xs[r][q]      = *(const float4*)(xr + q);
            *(float4*)&Xs[r][q + 16] = *(const float4*)(xr + q + 16);
        }
        {
            int kk = tid >> 4, cq = (tid & 15) * 4;
            int kg = kt * 32 + kk;
            float sd = sg[kg] * dV[kg];
            float4 b = *(const float4*)(Rv + (size_t)kg * NDIM + col0 + cq);
            b.x *= sd; b.y *= sd; b.z *= sd; b.w *= sd;
            *(float4*)&Ys[kk][cq] = b;
            int kg2 = kg + 16;
            float sd2 = sg[kg2] * dV[kg2];
            float4 b2 = *(const float4*)(Rv + (size_t)kg2 * NDIM + col0 + cq);
            b2.x *= sd2; b2.y *= sd2; b2.z *= sd2; b2.w *= sd2;
            *(float4*)&Ys[kk + 16][cq] = b2;
        }
        __syncthreads();
        #pragma unroll
        for (int kk = 0; kk < 32; ++kk) {
            float av[4] = {Xs[ty * 4 + 0][kk], Xs[ty * 4 + 1][kk],
                           Xs[ty * 4 + 2][kk], Xs[ty * 4 + 3][kk]};
            float4 B = *(const float4*)&Ys[kk][tx * 4];
            float bv[4] = {B.x, B.y, B.z, B.w};
            #pragma unroll
            for (int mm = 0; mm < 4; ++mm)
                #pragma unroll
                for (int nn = 0; nn < 4; ++nn)
                    acc[mm][nn] = fmaf(av[mm], bv[nn], acc[mm][nn]);
        }
        __syncthreads();
    }
    #pragma unroll
    for (int mm = 0; mm < 4; ++mm) {
        float du = dU[row0 + ty * 4 + mm];
        float4 st = make_float4(acc[mm][0] * du, acc[mm][1] * du,
                                acc[mm][2] * du, acc[mm][3] * du);
        *(float4*)&W[(size_t)(row0 + ty * 4 + mm) * NDIM + col0 + tx * 4] = st;
    }
}

// ---------------------------------------------------------------- final GEMM
// out[t,o] = sum_i x[t,i] * W[o,i].  128x64 tile, BK=32, 8x4 micro-tile.
__global__ __launch_bounds__(256) void gemm_kernel(const float* __restrict__ x,
                                                   const float* __restrict__ W,
                                                   float* __restrict__ out) {
    const int col0 = blockIdx.x * 64;
    const int row0 = blockIdx.y * 128;
    __shared__ float Xs[32][132];   // [k][token]
    __shared__ float Ys[32][68];    // [k][outcol]
    const int tid = threadIdx.x;
    const int tx = tid & 15, ty = tid >> 4;
    float acc[8][4] = {};
    for (int kt = 0; kt < 16; ++kt) {
        {
            int r = tid & 127;
            int ks = (tid >> 7) * 16;
            const float* xr = x + (size_t)(row0 + r) * NDIM + kt * 32 + ks;
            #pragma unroll
            for (int u = 0; u < 4; ++u) {
                float4 vv = *(const float4*)(xr + u * 4);
                Xs[ks + u * 4 + 0][r] = vv.x;
                Xs[ks + u * 4 + 1][r] = vv.y;
                Xs[ks + u * 4 + 2][r] = vv.z;
                Xs[ks + u * 4 + 3][r] = vv.w;
            }
        }
        {
            int o = tid & 63;
            int ks = (tid >> 6) * 4;
            const float* wr = W + (size_t)(col0 + o) * NDIM + kt * 32;
            float4 w0 = *(const float4*)(wr + ks);
            float4 w1 = *(const float4*)(wr + ks + 16);
            Ys[ks + 0][o] = w0.x; Ys[ks + 1][o] = w0.y;
            Ys[ks + 2][o] = w0.z; Ys[ks + 3][o] = w0.w;
            Ys[ks + 16][o] = w1.x; Ys[ks + 17][o] = w1.y;
            Ys[ks + 18][o] = w1.z; Ys[ks + 19][o] = w1.w;
        }
        __syncthreads();
        #pragma unroll
        for (int kk = 0; kk < 32; ++kk) {
            float4 A0 = *(const float4*)&Xs[kk][ty * 8];
            float4 A1 = *(const float4*)&Xs[kk][ty * 8 + 4];
            float4 B  = *(const float4*)&Ys[kk][tx * 4];
            float av[8] = {A0.x, A0.y, A0.z, A0.w, A1.x, A1.y, A1.z, A1.w};
            float bv[4] = {B.x, B.y, B.z, B.w};
            #pragma unroll
            for (int mm = 0; mm < 8; ++mm)
                #pragma unroll
                for (int nn = 0; nn < 4; ++nn)
                    acc[mm][nn] = fmaf(av[mm], bv[nn], acc[mm][nn]);
        }
        __syncthreads();
    }
    #pragma unroll
    for (int mm = 0; mm < 8; ++mm) {
        float4 st = make_float4(acc[mm][0], acc[mm][1], acc[mm][2], acc[mm][3]);
        *(float4*)&out[(size_t)(row0 + ty * 8 + mm) * NDIM + col0 + tx * 4] = st;
    }
}

// ---------------------------------------------------------------- host
extern "C" void kernel_launch(void* const* d_in, const int* in_sizes, int n_in,
                              void* d_out, int out_size, void* d_ws, size_t ws_size,
                              hipStream_t stream) {
    (void)in_sizes; (void)n_in; (void)out_size;
    const float* xp   = (const float*)d_in[0];
    const float* phiU = (const float*)d_in[1];
    const float* dUp  = (const float*)d_in[2];
    const float* phiV = (const float*)d_in[3];
    const float* dVp  = (const float*)d_in[4];
    const float* sgp  = (const float*)d_in[5];
    float* out = (float*)d_out;
    float* wsf = (float*)d_ws;

    // Pick largest G (rotation blocks per matrix) that fits the workspace.
    int G = 16;
    while (G > 1) {
        size_t needFloats = (size_t)4 * PTOT + (size_t)2 * G * MAT
                          + (size_t)G * MAT + MAT;
        if (needFloats * 4 <= ws_size) break;
        G >>= 1;
    }
    const int R = NPAIR / G;   // exact for G in {1,2,4,8,16}

    float2* csU = (float2*)wsf;
    float2* csV = csU + PTOT;
    float* bufA = wsf + (size_t)4 * PTOT;
    float* bufB = bufA + (size_t)2 * G * MAT;
    const int capB = (G > 1) ? G / 2 : 1;
    float* Wbuf = (G > 1) ? (bufB + (size_t)2 * capB * MAT) : bufB;

    // 1) trig (fan-padded layout)
    trig_kernel<<<dim3((2 * PTOT + 255) / 256), 256, 0, stream>>>(phiU, phiV, csU, csV);

    // 2) block products (both sides in one launch)
    group_kernel<<<dim3(16, G, 2), 64, 0, stream>>>(csU, csV, bufA, R, G);

    // 3) tree combine: log2(G) rounds, ping-pong bufA <-> bufB
    const float* cur = bufA;
    float* oth = bufB;
    int curCap = G, othCap = capB;
    for (int P = G / 2, half = 1; P >= 1; P >>= 1, half <<= 1) {
        combine_kernel<<<dim3(64, 1, 2 * P), 256, 0, stream>>>(cur, oth, curCap, othCap, half, R, P);
        const float* t = cur; cur = oth; oth = (float*)t;
        int tc = curCap; curCap = othCap; othCap = tc;
    }
    const float* Ru = cur;
    const float* Rv = cur + (size_t)curCap * MAT;

    // 4) W assembly
    wasm_kernel<<<dim3(64), 256, 0, stream>>>(Ru, Rv, dUp, dVp, sgp, Wbuf);

    // 5) out = x * W^T
    gemm_kernel<<<dim3(8, 256), 256, 0, stream>>>(xp, Wbuf, out);
}